// Round 5
// baseline (727.497 us; speedup 1.0000x reference)
//
#include <hip/hip_runtime.h>
#include <stdint.h>

#define B_    4
#define H_    16
#define S_    2048
#define D_    64
#define SCALE_LOG2E 0.1803368801111244f   // 0.125 * log2(e)

typedef __bf16 bf16x8 __attribute__((ext_vector_type(8)));
typedef __bf16 bf16x4 __attribute__((ext_vector_type(4)));
typedef float  f32x4  __attribute__((ext_vector_type(4)));

// ---- prepass: K fp32 [bh][s][d] -> bf16 slice images
// slice (bh,e,w) = 2048B: 16 rows (k'=0..15) x 128B (d), byte cb holds d-byte cb ^ ((k'&7)<<4)
__global__ __launch_bounds__(256)
void prep_k(const float* __restrict__ K, __bf16* __restrict__ img) {
    int t     = blockIdx.x * 256 + threadIdx.x;     // 1,048,576 x 16B chunks
    int slice = t >> 7;
    int L     = (t & 127) << 4;
    int kp    = L >> 7;
    int cb    = L & 127;
    int scb   = cb ^ ((kp & 7) << 4);
    int w  = slice & 3;
    int e  = (slice >> 2) & 31;
    int bh = slice >> 7;
    int s  = e * 64 + w * 16 + kp;
    const float* src = K + ((size_t)bh * S_ + s) * D_ + (scb >> 1);
    float4 a = *reinterpret_cast<const float4*>(src);
    float4 b = *reinterpret_cast<const float4*>(src + 4);
    bf16x8 wv = { (__bf16)a.x,(__bf16)a.y,(__bf16)a.z,(__bf16)a.w,
                  (__bf16)b.x,(__bf16)b.y,(__bf16)b.z,(__bf16)b.w };
    *reinterpret_cast<bf16x8*>((char*)img + ((size_t)t << 4)) = wv;
}

// ---- prepass: V fp32 [bh][s][d] -> transposed bf16 slice images
// slice (bh,e,w) = 2048B: 64 rows (d) x 32B (k'=0..15), linear
__global__ __launch_bounds__(256)
void prep_v(const float* __restrict__ V, __bf16* __restrict__ img) {
    __shared__ float Ls[64][65];
    const int tid = threadIdx.x;
    const int bh = blockIdx.x >> 5, e = blockIdx.x & 31;
    const float* Vp = V + ((size_t)bh * S_ + e * 64) * D_;
    for (int i = tid; i < 1024; i += 256) {
        int r = i >> 4, c = (i & 15) << 2;
        float4 v = reinterpret_cast<const float4*>(Vp)[i];
        Ls[r][c] = v.x; Ls[r][c+1] = v.y; Ls[r][c+2] = v.z; Ls[r][c+3] = v.w;
    }
    __syncthreads();
    char* base = (char*)img + ((size_t)(bh * 32 + e) * 4) * 2048;
    #pragma unroll
    for (int m = tid; m < 512; m += 256) {          // chunk = (d, w, half)
        int d = m >> 3, w = (m >> 1) & 3, half = m & 1;
        bf16x8 wv;
        #pragma unroll
        for (int j = 0; j < 8; ++j)
            wv[j] = (__bf16)Ls[w * 16 + half * 8 + j][d];
        *reinterpret_cast<bf16x8*>(base + (size_t)w * 2048 + d * 32 + half * 16) = wv;
    }
}

__device__ __forceinline__ void gload16(const void* g, void* l) {
    __builtin_amdgcn_global_load_lds(
        (const __attribute__((address_space(1))) void*)g,
        (__attribute__((address_space(3))) void*)l, 16, 0, 0);
}

__global__ __launch_bounds__(256, 3)
void sdpa_main(const float* __restrict__ Q, const __bf16* __restrict__ Kimg,
               const __bf16* __restrict__ Vimg, const int* __restrict__ mask,
               float* __restrict__ ctx_out, float* __restrict__ attn_out)
{
    // 4 wave strips x 12288B (3 bufs x {K 2048 + V 2048}) + 1KB lsum
    __shared__ __align__(16) char smem[50176];

    const int tid = threadIdx.x;
    const int lane = tid & 63, wid = tid >> 6;
    const int l15 = lane & 15, lhi = lane >> 4;
    const int sw = (l15 & 7) << 4;

    const int orig = blockIdx.x, cpx = gridDim.x >> 3;
    const int bid = (orig & 7) * cpx + (orig >> 3);
    const int qt = bid & 31, bh = bid >> 5, b = bh >> 4;

    const char* kimg0 = (const char*)Kimg + (size_t)bh * 262144 + wid * 2048;
    const char* vimg0 = (const char*)Vimg + (size_t)bh * 262144 + wid * 2048;
    char* strip = smem + wid * 12288;

    auto stageK = [&](int t) {
        int e = (t + qt) & 31;
        const char* s = kimg0 + (size_t)e * 8192 + lane * 16;
        char* d = strip + (t % 3) * 4096;
        gload16(s, d); gload16(s + 1024, d + 1024);
    };
    auto stageV = [&](int t) {
        int e = (t + qt) & 31;
        const char* s = vimg0 + (size_t)e * 8192 + lane * 16;
        char* d = strip + (t % 3) * 4096 + 2048;
        gload16(s, d); gload16(s + 1024, d + 1024);
    };

    // Q fragments as B-operand: lane l15 = q-col (rows qt*64 + rb*16 + l15)
    bf16x8 bQ[4][2];
    #pragma unroll
    for (int rb = 0; rb < 4; ++rb) {
        const float* qrow = Q + ((size_t)bh * S_ + qt * 64 + rb * 16 + l15) * D_ + lhi * 8;
        float4 a = *reinterpret_cast<const float4*>(qrow);
        float4 c = *reinterpret_cast<const float4*>(qrow + 4);
        bf16x8 w0 = { (__bf16)a.x,(__bf16)a.y,(__bf16)a.z,(__bf16)a.w,
                      (__bf16)c.x,(__bf16)c.y,(__bf16)c.z,(__bf16)c.w };
        bQ[rb][0] = w0;
        a = *reinterpret_cast<const float4*>(qrow + 32);
        c = *reinterpret_cast<const float4*>(qrow + 36);
        bf16x8 w1 = { (__bf16)a.x,(__bf16)a.y,(__bf16)a.z,(__bf16)a.w,
                      (__bf16)c.x,(__bf16)c.y,(__bf16)c.z,(__bf16)c.w };
        bQ[rb][1] = w1;
    }

    // mask bits: per lane, k = e*64 + wid*16 + lhi*4 + r -> nibble bit r of tile e
    uint32_t mw[4] = {0, 0, 0, 0};
    {
        const int* mrow = mask + b * S_ + wid * 16 + lhi * 4;
        #pragma unroll
        for (int e = 0; e < 32; ++e) {
            int4 mm = *reinterpret_cast<const int4*>(mrow + e * 64);
            uint32_t nib = (mm.x ? 1u : 0u) | (mm.y ? 2u : 0u) |
                           (mm.z ? 4u : 0u) | (mm.w ? 8u : 0u);
            mw[e >> 3] |= nib << ((e & 7) * 4);
        }
    }

    // ---------------- pass 1: row sums (wave-private, 32 tiles) ----------------
    float ls[4] = {0.f, 0.f, 0.f, 0.f};
    stageK(0);
    for (int t = 0; t < 32; ++t) {
        if (t < 31) {
            stageK(t + 1);
            asm volatile("s_waitcnt vmcnt(2)" ::: "memory");
        } else {
            asm volatile("s_waitcnt vmcnt(0)" ::: "memory");
        }
        const char* kb = strip + (t % 3) * 4096;
        bf16x8 kf0 = *reinterpret_cast<const bf16x8*>(kb + l15 * 128 + ((lhi * 16) ^ sw));
        bf16x8 kf1 = *reinterpret_cast<const bf16x8*>(kb + l15 * 128 + ((64 + lhi * 16) ^ sw));
        int e = (t + qt) & 31;
        uint32_t nib = (mw[e >> 3] >> ((e & 7) * 4)) & 15u;
        #pragma unroll
        for (int rb = 0; rb < 4; ++rb) {
            f32x4 acc = {0.f, 0.f, 0.f, 0.f};
            acc = __builtin_amdgcn_mfma_f32_16x16x32_bf16(kf0, bQ[rb][0], acc, 0, 0, 0);
            acc = __builtin_amdgcn_mfma_f32_16x16x32_bf16(kf1, bQ[rb][1], acc, 0, 0, 0);
            float p0 = (nib & 1u) ? 0.f : exp2f(acc[0] * SCALE_LOG2E);
            float p1 = (nib & 2u) ? 0.f : exp2f(acc[1] * SCALE_LOG2E);
            float p2 = (nib & 4u) ? 0.f : exp2f(acc[2] * SCALE_LOG2E);
            float p3 = (nib & 8u) ? 0.f : exp2f(acc[3] * SCALE_LOG2E);
            ls[rb] += (p0 + p1) + (p2 + p3);
        }
    }

    // reduce lsum: over lhi (shfl) then over waves (LDS)
    #pragma unroll
    for (int rb = 0; rb < 4; ++rb) {
        ls[rb] += __shfl_xor(ls[rb], 16);
        ls[rb] += __shfl_xor(ls[rb], 32);
    }
    float* lsb = reinterpret_cast<float*>(smem + 49152);
    if (lhi == 0) {
        #pragma unroll
        for (int rb = 0; rb < 4; ++rb) lsb[(wid * 4 + rb) * 16 + l15] = ls[rb];
    }
    __syncthreads();
    float rl[4];
    #pragma unroll
    for (int rb = 0; rb < 4; ++rb) {
        float tot = (lsb[rb * 16 + l15] + lsb[(4 + rb) * 16 + l15]) +
                    (lsb[(8 + rb) * 16 + l15] + lsb[(12 + rb) * 16 + l15]);
        rl[rb] = 1.0f / tot;
    }

    // ---------------- pass 2: 16 tile-pairs ----------------
    f32x4 ctx[4][4];
    #pragma unroll
    for (int rb = 0; rb < 4; ++rb)
        #pragma unroll
        for (int db = 0; db < 4; ++db) ctx[rb][db] = (f32x4){0.f, 0.f, 0.f, 0.f};

    const size_t arowq = (size_t)bh * S_ + (size_t)qt * 64;

    auto qkexp = [&](int t, bf16x4* pk) {
        const char* kb = strip + (t % 3) * 4096;
        bf16x8 kf0 = *reinterpret_cast<const bf16x8*>(kb + l15 * 128 + ((lhi * 16) ^ sw));
        bf16x8 kf1 = *reinterpret_cast<const bf16x8*>(kb + l15 * 128 + ((64 + lhi * 16) ^ sw));
        int e = (t + qt) & 31;
        uint32_t nib = (mw[e >> 3] >> ((e & 7) * 4)) & 15u;
        size_t colbase = (size_t)e * 64 + wid * 16 + lhi * 4;
        #pragma unroll
        for (int rb = 0; rb < 4; ++rb) {
            f32x4 acc = {0.f, 0.f, 0.f, 0.f};
            acc = __builtin_amdgcn_mfma_f32_16x16x32_bf16(kf0, bQ[rb][0], acc, 0, 0, 0);
            acc = __builtin_amdgcn_mfma_f32_16x16x32_bf16(kf1, bQ[rb][1], acc, 0, 0, 0);
            float p0 = (nib & 1u) ? 0.f : exp2f(acc[0] * SCALE_LOG2E) * rl[rb];
            float p1 = (nib & 2u) ? 0.f : exp2f(acc[1] * SCALE_LOG2E) * rl[rb];
            float p2 = (nib & 4u) ? 0.f : exp2f(acc[2] * SCALE_LOG2E) * rl[rb];
            float p3 = (nib & 8u) ? 0.f : exp2f(acc[3] * SCALE_LOG2E) * rl[rb];
            float4 st = { p0, p1, p2, p3 };
            *reinterpret_cast<float4*>(&attn_out[(arowq + rb * 16 + l15) * S_ + colbase]) = st;
            bf16x4 pkk = { (__bf16)p0, (__bf16)p1, (__bf16)p2, (__bf16)p3 };
            pk[rb] = pkk;
        }
    };

    stageK(0); stageV(0);
    bf16x4 pkA[4], pkB[4];
    for (int tp = 0; tp < 16; ++tp) {
        int t0 = tp * 2, t1 = t0 + 1;
        // body t0
        stageK(t1); stageV(t1);
        asm volatile("s_waitcnt vmcnt(4)" ::: "memory");
        qkexp(t0, pkA);
        // body t1
        if (tp < 15) {
            stageK(t1 + 1); stageV(t1 + 1);
            asm volatile("s_waitcnt vmcnt(4)" ::: "memory");
        } else {
            asm volatile("s_waitcnt vmcnt(0)" ::: "memory");
        }
        qkexp(t1, pkB);
        // PV over the pair (k-order: [t0: lhi*4+r | t1: lhi*4+r], matched on A and B)
        const char* vb0 = strip + (t0 % 3) * 4096 + 2048;
        const char* vb1 = strip + (t1 % 3) * 4096 + 2048;
        #pragma unroll
        for (int db = 0; db < 4; ++db) {
            int off = (db * 16 + l15) * 32 + lhi * 8;
            bf16x4 v0 = *reinterpret_cast<const bf16x4*>(vb0 + off);
            bf16x4 v1 = *reinterpret_cast<const bf16x4*>(vb1 + off);
            bf16x8 Bv;
            Bv[0]=v0[0]; Bv[1]=v0[1]; Bv[2]=v0[2]; Bv[3]=v0[3];
            Bv[4]=v1[0]; Bv[5]=v1[1]; Bv[6]=v1[2]; Bv[7]=v1[3];
            #pragma unroll
            for (int rb = 0; rb < 4; ++rb) {
                bf16x8 Av;
                Av[0]=pkA[rb][0]; Av[1]=pkA[rb][1]; Av[2]=pkA[rb][2]; Av[3]=pkA[rb][3];
                Av[4]=pkB[rb][0]; Av[5]=pkB[rb][1]; Av[6]=pkB[rb][2]; Av[7]=pkB[rb][3];
                ctx[rb][db] = __builtin_amdgcn_mfma_f32_16x16x32_bf16(Av, Bv, ctx[rb][db], 0, 0, 0);
            }
        }
    }

    // ---------------- cross-wave ctx reduce (aliases staging strips) ----------------
    __syncthreads();
    float* Cred = reinterpret_cast<float*>(smem);   // 64 x 65 floats
    for (int ph = 0; ph < 4; ++ph) {
        if (wid == ph) {
            #pragma unroll
            for (int rb = 0; rb < 4; ++rb)
                #pragma unroll
                for (int db = 0; db < 4; ++db)
                    #pragma unroll
                    for (int r = 0; r < 4; ++r) {
                        float* c = &Cred[(rb * 16 + lhi * 4 + r) * 65 + db * 16 + l15];
                        if (ph == 0) *c = ctx[rb][db][r];
                        else         *c += ctx[rb][db][r];
                    }
        }
        __syncthreads();
    }
    for (int i = tid; i < 4096; i += 256) {
        int q = i >> 6, d = i & 63;
        ctx_out[(arowq + q) * D_ + d] = Cred[q * 65 + d];
    }
}

extern "C" void kernel_launch(void* const* d_in, const int* in_sizes, int n_in,
                              void* d_out, int out_size, void* d_ws, size_t ws_size,
                              hipStream_t stream) {
    const float* Q    = (const float*)d_in[0];
    const float* K    = (const float*)d_in[1];
    const float* V    = (const float*)d_in[2];
    const int*   mask = (const int*)d_in[3];

    float* ctx_out  = (float*)d_out;
    float* attn_out = ctx_out + (size_t)B_ * H_ * S_ * D_;

    __bf16* Kimg = (__bf16*)d_ws;                              // 16.8 MB
    __bf16* Vimg = Kimg + (size_t)B_ * H_ * S_ * D_;           // 16.8 MB

    prep_k<<<4096, 256, 0, stream>>>(K, Kimg);
    prep_v<<<B_ * H_ * 32, 256, 0, stream>>>(V, Vimg);
    sdpa_main<<<B_ * H_ * 32, 256, 0, stream>>>(Q, Kimg, Vimg, mask, ctx_out, attn_out);
}

// Round 6
// 676.249 us; speedup vs baseline: 1.0758x; 1.0758x over previous
//
#include <hip/hip_runtime.h>
#include <stdint.h>

#define B_    4
#define H_    16
#define S_    2048
#define D_    64
#define SCALE_LOG2E 0.1803368801111244f   // 0.125 * log2(e)

typedef __bf16 bf16x8 __attribute__((ext_vector_type(8)));
typedef __bf16 bf16x4 __attribute__((ext_vector_type(4)));
typedef float  f32x4  __attribute__((ext_vector_type(4)));

// ---------- prepass: K fp32 -> bf16, same [bh][s][d] layout ----------
__global__ __launch_bounds__(256)
void prep_k(const float* __restrict__ K, __bf16* __restrict__ Kb) {
    size_t i = (size_t)blockIdx.x * 256 + threadIdx.x;   // 8 elems per thread
    const float4* src = reinterpret_cast<const float4*>(K) + i * 2;
    float4 a = src[0], b = src[1];
    bf16x8 w = { (__bf16)a.x,(__bf16)a.y,(__bf16)a.z,(__bf16)a.w,
                 (__bf16)b.x,(__bf16)b.y,(__bf16)b.z,(__bf16)b.w };
    reinterpret_cast<bf16x8*>(Kb)[i] = w;
}

// ---------- prepass: V fp32 [bh][s][d] -> bf16 transposed [bh][d][s] ----------
__global__ __launch_bounds__(256)
void prep_v(const float* __restrict__ V, __bf16* __restrict__ Vt) {
    __shared__ float Ls[64][65];
    const int tid = threadIdx.x;
    const int bh = blockIdx.x >> 5, st = blockIdx.x & 31;
    const float* Vp = V + ((size_t)bh * S_ + st * 64) * D_;
    for (int i = tid; i < 1024; i += 256) {           // 64x64 fp32 tile
        int r = i >> 4, c = (i & 15) << 2;
        float4 v = reinterpret_cast<const float4*>(Vp)[i];
        Ls[r][c] = v.x; Ls[r][c+1] = v.y; Ls[r][c+2] = v.z; Ls[r][c+3] = v.w;
    }
    __syncthreads();
    const int d = tid >> 2, sc = (tid & 3) * 16;
    __bf16* dst = Vt + ((size_t)bh * D_ + d) * S_ + st * 64 + sc;
    bf16x8 w0, w1;
    #pragma unroll
    for (int j = 0; j < 8; ++j) w0[j] = (__bf16)Ls[sc + j][d];
    #pragma unroll
    for (int j = 0; j < 8; ++j) w1[j] = (__bf16)Ls[sc + 8 + j][d];
    *reinterpret_cast<bf16x8*>(dst)     = w0;
    *reinterpret_cast<bf16x8*>(dst + 8) = w1;
}

// ---------- main: global-direct fragments, barrier-free hot loop ----------
__global__ __launch_bounds__(256, 2)
void sdpa_main(const float* __restrict__ Q, const __bf16* __restrict__ Kb,
               const __bf16* __restrict__ Vt, const int* __restrict__ mask,
               float* __restrict__ ctx_out, float* __restrict__ attn_out)
{
    __shared__ __align__(16) float shbuf[64 * 65];   // lsum scratch, then ctx reduce

    const int tid  = threadIdx.x;
    const int lane = tid & 63, wid = tid >> 6;
    const int l15  = lane & 15, lhi = lane >> 4;
    const int par  = wid & 1;        // tile parity this wave owns
    const int sb   = wid >> 1;       // 32-wide k-slice within tile

    const int orig = blockIdx.x, cpx = gridDim.x >> 3;
    const int bid  = (orig & 7) * cpx + (orig >> 3);
    const int qt = bid & 31, bh = bid >> 5, b = bh >> 4;

    const __bf16* Kp = Kb + (size_t)bh * S_ * D_;
    const __bf16* Vp = Vt + (size_t)bh * D_ * S_;

    // tile schedule: e = 2*((tt+qt)&15) + par  (16 tiles per wave)
    int etab[16];
    #pragma unroll
    for (int tt = 0; tt < 16; ++tt) etab[tt] = (((tt + qt) & 15) << 1) | par;

    // Q fragments as B-operand: lane l15 = q-col (rows qt*64 + rb*16 + l15)
    bf16x8 bQ[4][2];
    #pragma unroll
    for (int rb = 0; rb < 4; ++rb) {
        const float* qrow = Q + ((size_t)bh * S_ + qt * 64 + rb * 16 + l15) * D_ + lhi * 8;
        float4 a = *reinterpret_cast<const float4*>(qrow);
        float4 c = *reinterpret_cast<const float4*>(qrow + 4);
        bf16x8 w0 = { (__bf16)a.x,(__bf16)a.y,(__bf16)a.z,(__bf16)a.w,
                      (__bf16)c.x,(__bf16)c.y,(__bf16)c.z,(__bf16)c.w };
        bQ[rb][0] = w0;
        a = *reinterpret_cast<const float4*>(qrow + 32);
        c = *reinterpret_cast<const float4*>(qrow + 36);
        bf16x8 w1 = { (__bf16)a.x,(__bf16)a.y,(__bf16)a.z,(__bf16)a.w,
                      (__bf16)c.x,(__bf16)c.y,(__bf16)c.z,(__bf16)c.w };
        bQ[rb][1] = w1;
    }

    // mask bits: tile tt, ksub, r -> word tt>>2, bit (tt&3)*8 + ksub*4 + r (set = masked)
    uint32_t mwv[4] = {0, 0, 0, 0};
    {
        const int* mrow = mask + b * S_ + sb * 32 + lhi * 4;
        #pragma unroll
        for (int tt = 0; tt < 16; ++tt) {
            #pragma unroll
            for (int ksub = 0; ksub < 2; ++ksub) {
                int4 mm = *reinterpret_cast<const int4*>(mrow + etab[tt] * 64 + ksub * 16);
                uint32_t nib = (mm.x ? 1u : 0u) | (mm.y ? 2u : 0u) |
                               (mm.z ? 4u : 0u) | (mm.w ? 8u : 0u);
                mwv[tt >> 2] |= nib << (((tt & 3) * 8) + ksub * 4);
            }
        }
    }

    // K fragment loader: kf[buf][ksub][kd]
    bf16x8 kf[2][2][2];
    auto loadK = [&](int bufi, int tt) {
        const __bf16* kp = Kp + ((size_t)(etab[tt] * 64 + sb * 32 + l15)) * 64 + lhi * 8;
        kf[bufi][0][0] = *reinterpret_cast<const bf16x8*>(kp);
        kf[bufi][0][1] = *reinterpret_cast<const bf16x8*>(kp + 32);
        kf[bufi][1][0] = *reinterpret_cast<const bf16x8*>(kp + 1024);
        kf[bufi][1][1] = *reinterpret_cast<const bf16x8*>(kp + 1024 + 32);
    };
    // V fragment loader: vv[buf][db][half], V^T rows d, cols k
    bf16x4 vv[2][4][2];
    auto loadV = [&](int bufi, int tt) {
        int scol = etab[tt] * 64 + sb * 32 + lhi * 4;
        #pragma unroll
        for (int db = 0; db < 4; ++db) {
            const __bf16* vp = Vp + (size_t)(db * 16 + l15) * S_ + scol;
            vv[bufi][db][0] = *reinterpret_cast<const bf16x4*>(vp);
            vv[bufi][db][1] = *reinterpret_cast<const bf16x4*>(vp + 16);
        }
    };

    // ---------------- pass 1: row sums ----------------
    float ls[4] = {0.f, 0.f, 0.f, 0.f};
    loadK(0, 0);
    #pragma unroll
    for (int tt = 0; tt < 16; ++tt) {
        if (tt + 1 < 16) loadK((tt + 1) & 1, tt + 1);
        const int cur = tt & 1;
        #pragma unroll
        for (int ksub = 0; ksub < 2; ++ksub) {
            uint32_t nib = (mwv[tt >> 2] >> (((tt & 3) * 8) + ksub * 4)) & 15u;
            #pragma unroll
            for (int rb = 0; rb < 4; ++rb) {
                f32x4 acc = {0.f, 0.f, 0.f, 0.f};
                acc = __builtin_amdgcn_mfma_f32_16x16x32_bf16(kf[cur][ksub][0], bQ[rb][0], acc, 0, 0, 0);
                acc = __builtin_amdgcn_mfma_f32_16x16x32_bf16(kf[cur][ksub][1], bQ[rb][1], acc, 0, 0, 0);
                float p0 = (nib & 1u) ? 0.f : exp2f(acc[0] * SCALE_LOG2E);
                float p1 = (nib & 2u) ? 0.f : exp2f(acc[1] * SCALE_LOG2E);
                float p2 = (nib & 4u) ? 0.f : exp2f(acc[2] * SCALE_LOG2E);
                float p3 = (nib & 8u) ? 0.f : exp2f(acc[3] * SCALE_LOG2E);
                ls[rb] += (p0 + p1) + (p2 + p3);
            }
        }
    }

    // reduce lsum: over lhi (shfl), then across 4 waves (LDS)
    #pragma unroll
    for (int rb = 0; rb < 4; ++rb) {
        ls[rb] += __shfl_xor(ls[rb], 16);
        ls[rb] += __shfl_xor(ls[rb], 32);
    }
    if (lhi == 0) {
        #pragma unroll
        for (int rb = 0; rb < 4; ++rb) shbuf[(wid * 4 + rb) * 16 + l15] = ls[rb];
    }
    __syncthreads();
    float rl[4];
    #pragma unroll
    for (int rb = 0; rb < 4; ++rb) {
        float tot = (shbuf[rb * 16 + l15] + shbuf[(4 + rb) * 16 + l15]) +
                    (shbuf[(8 + rb) * 16 + l15] + shbuf[(12 + rb) * 16 + l15]);
        rl[rb] = 1.0f / tot;
    }

    // ---------------- pass 2: attn store (full 128B lines) + PV ----------------
    f32x4 ctx[4][4];
    #pragma unroll
    for (int rb = 0; rb < 4; ++rb)
        #pragma unroll
        for (int db = 0; db < 4; ++db) ctx[rb][db] = (f32x4){0.f, 0.f, 0.f, 0.f};

    const size_t arowq = (size_t)bh * S_ + (size_t)qt * 64;

    loadK(0, 0); loadV(0, 0);
    bf16x4 pk[2][4];
    #pragma unroll
    for (int tt = 0; tt < 16; ++tt) {
        if (tt + 1 < 16) { loadK((tt + 1) & 1, tt + 1); loadV((tt + 1) & 1, tt + 1); }
        const int cur = tt & 1;
        const int e = etab[tt];
        const int colbase = e * 64 + sb * 32;
        // QK^T + exp + normalized store; rb outer so the two ksub stores per row are adjacent
        #pragma unroll
        for (int rb = 0; rb < 4; ++rb) {
            float* arow = attn_out + (arowq + rb * 16 + l15) * S_ + colbase + lhi * 4;
            #pragma unroll
            for (int ksub = 0; ksub < 2; ++ksub) {
                uint32_t nib = (mwv[tt >> 2] >> (((tt & 3) * 8) + ksub * 4)) & 15u;
                f32x4 acc = {0.f, 0.f, 0.f, 0.f};
                acc = __builtin_amdgcn_mfma_f32_16x16x32_bf16(kf[cur][ksub][0], bQ[rb][0], acc, 0, 0, 0);
                acc = __builtin_amdgcn_mfma_f32_16x16x32_bf16(kf[cur][ksub][1], bQ[rb][1], acc, 0, 0, 0);
                float p0 = (nib & 1u) ? 0.f : exp2f(acc[0] * SCALE_LOG2E) * rl[rb];
                float p1 = (nib & 2u) ? 0.f : exp2f(acc[1] * SCALE_LOG2E) * rl[rb];
                float p2 = (nib & 4u) ? 0.f : exp2f(acc[2] * SCALE_LOG2E) * rl[rb];
                float p3 = (nib & 8u) ? 0.f : exp2f(acc[3] * SCALE_LOG2E) * rl[rb];
                float4 st = { p0, p1, p2, p3 };
                *reinterpret_cast<float4*>(arow + ksub * 16) = st;
                bf16x4 pkk = { (__bf16)p0, (__bf16)p1, (__bf16)p2, (__bf16)p3 };
                pk[ksub][rb] = pkk;
            }
        }
        // PV: kk = lhi*8 + j  <->  k_local = (j>>2)*16 + lhi*4 + (j&3), matched on A and B
        #pragma unroll
        for (int db = 0; db < 4; ++db) {
            bf16x8 Bv;
            Bv[0]=vv[cur][db][0][0]; Bv[1]=vv[cur][db][0][1];
            Bv[2]=vv[cur][db][0][2]; Bv[3]=vv[cur][db][0][3];
            Bv[4]=vv[cur][db][1][0]; Bv[5]=vv[cur][db][1][1];
            Bv[6]=vv[cur][db][1][2]; Bv[7]=vv[cur][db][1][3];
            #pragma unroll
            for (int rb = 0; rb < 4; ++rb) {
                bf16x8 Av;
                Av[0]=pk[0][rb][0]; Av[1]=pk[0][rb][1]; Av[2]=pk[0][rb][2]; Av[3]=pk[0][rb][3];
                Av[4]=pk[1][rb][0]; Av[5]=pk[1][rb][1]; Av[6]=pk[1][rb][2]; Av[7]=pk[1][rb][3];
                ctx[rb][db] = __builtin_amdgcn_mfma_f32_16x16x32_bf16(Av, Bv, ctx[rb][db], 0, 0, 0);
            }
        }
    }

    // ---------------- cross-wave ctx reduce ----------------
    __syncthreads();
    for (int ph = 0; ph < 4; ++ph) {
        if (wid == ph) {
            #pragma unroll
            for (int rb = 0; rb < 4; ++rb)
                #pragma unroll
                for (int db = 0; db < 4; ++db)
                    #pragma unroll
                    for (int r = 0; r < 4; ++r) {
                        float* c = &shbuf[(rb * 16 + lhi * 4 + r) * 65 + db * 16 + l15];
                        if (ph == 0) *c = ctx[rb][db][r];
                        else         *c += ctx[rb][db][r];
                    }
        }
        __syncthreads();
    }
    for (int i = tid; i < 4096; i += 256) {
        int q = i >> 6, d = i & 63;
        ctx_out[(arowq + q) * D_ + d] = shbuf[q * 65 + d];
    }
}

extern "C" void kernel_launch(void* const* d_in, const int* in_sizes, int n_in,
                              void* d_out, int out_size, void* d_ws, size_t ws_size,
                              hipStream_t stream) {
    const float* Q    = (const float*)d_in[0];
    const float* K    = (const float*)d_in[1];
    const float* V    = (const float*)d_in[2];
    const int*   mask = (const int*)d_in[3];

    float* ctx_out  = (float*)d_out;
    float* attn_out = ctx_out + (size_t)B_ * H_ * S_ * D_;

    __bf16* Kb = (__bf16*)d_ws;                              // 16.8 MB
    __bf16* Vt = Kb + (size_t)B_ * H_ * S_ * D_;             // 16.8 MB

    const int elems = B_ * H_ * S_ * D_;                     // 8.4M
    prep_k<<<elems / (256 * 8), 256, 0, stream>>>(K, Kb);
    prep_v<<<B_ * H_ * 32, 256, 0, stream>>>(V, Vt);
    sdpa_main<<<B_ * H_ * 32, 256, 0, stream>>>(Q, Kb, Vt, mask, ctx_out, attn_out);
}